// Round 7
// baseline (648.087 us; speedup 1.0000x reference)
//
#include <hip/hip_runtime.h>

#define FA 75
#define FB 12
#define CC 100
#define NN 20000
#define EE 40000
#define GG 1000
#define BN_EPS 1e-5f
#define XPAD 76     // x rows padded to 76 floats -> 304 B, 16-B aligned

// msg tiling: wave = 4 edges x 100 channels (lane=channel), block = 8 waves
#define MSG_T    4          // edges per wave
#define MSG_WAVES 8
#define IT       12         // i-rows per LDS tile
#define NTILES   7          // 7*12 = 84 >= 75 (i>=75 rows zero-padded)
#define TILE_DW  16384      // padded dwords per tile (64 KB)
// tile layout (dword offsets): w0[IT*100]*4 | w1 | w2 | bias[IT*100]
#define TOFF_W1  4800
#define TOFF_W2  9600
#define TOFF_B   14400

// workspace layout (float offsets)
#define OFF_W1G   0                     // 7 * 16384 = 114,688
#define OFF_XP    114688                // 20000*76 + slack = 1,520,256
#define OFF_AGGT  1634944               // [C, N] = 2,000,000
#define OFF_S     3634944               // [C, G] = 100,000
#define OFF_SACC  3734944               // 200 (sum, sumsq per channel)
#define OFF_START 3735144               // int start[G+1]

__device__ __forceinline__ float bcast_lane(float v, int sl) {
    return __int_as_float(__builtin_amdgcn_readlane(__float_as_int(v), sl));
}
__device__ __forceinline__ float uni(float v) {
    return __int_as_float(__builtin_amdgcn_readfirstlane(__float_as_int(v)));
}

// prep: (a) pack W1+b1 into tiled SoA layout W1g (zero rows for i>=75),
// (b) molecule start offsets, (c) pad-pack x into 76-float rows.
__global__ __launch_bounds__(256) void prep_kernel(
    const float* __restrict__ W1, const float* __restrict__ b1,
    const float* __restrict__ x, const int* __restrict__ batch,
    float* __restrict__ W1g, float* __restrict__ xp, int* __restrict__ start)
{
    int idx = blockIdx.x * 256 + threadIdx.x;
    if (idx < NTILES * 15600) {
        int t = idx / 15600;
        int r = idx - t * 15600;
        float v = 0.f;
        if (r < 14400) {                 // w sections: s=0,1,2 -> b = 4s+q
            int s = r / 4800;
            int r2 = r - s * 4800;
            int rc = r2 >> 2, q = r2 & 3;
            int il = rc / 100, c = rc - il * 100;
            int i = t * IT + il;
            if (i < FA) v = W1[(4 * s + q) * 7500 + i * CC + c];
        } else {                         // bias section
            int r2 = r - 14400;
            int il = r2 / 100, c = r2 - il * 100;
            int i = t * IT + il;
            if (i < FA) v = b1[i * CC + c];
        }
        W1g[(size_t)t * TILE_DW + r] = v;
    } else if (idx < NTILES * 15600 + NN) {
        int n = idx - NTILES * 15600;
        int b = batch[n];
        int prev = (n == 0) ? -1 : batch[n - 1];
        for (int g = prev + 1; g <= b; ++g) start[g] = n;
        if (n == NN - 1)
            for (int g = b + 1; g <= GG; ++g) start[g] = NN;
    } else {
        int t = idx - (NTILES * 15600 + NN);
        if (t < NN * XPAD) {
            int n = t / XPAD;
            int i = t - n * XPAD;
            xp[t] = (i < FA) ? x[n * FA + i] : 0.f;
        }
    }
}

// Fused NNConv message + scatter, lane = CHANNEL layout.
// wave = 4 edges x 100 channels (lane -> c, c+64); block = 8 waves = 32 edges.
// Weights stream global->LDS in 64 KB tiles, read DENSELY per lane (every
// LDS byte consumed; R6's broadcast reads wasted 63/64 of LDS BW).
// Edge-uniform data (ea, x_i) rides the scalar pipe (readfirstlane/readlane).
__global__ __launch_bounds__(512, 4) void msg_kernel(
    const float* __restrict__ xp, const float* __restrict__ edge_attr,
    const float* __restrict__ W1g, const int* __restrict__ eidx,
    float* __restrict__ aggT)
{
    __shared__ float wlds[TILE_DW];
    const int tid = threadIdx.x;
    const int lane = tid & 63;
    const int wv = tid >> 6;                       // 0..7
    const int ebase = blockIdx.x * (MSG_WAVES * MSG_T) + wv * MSG_T;

    // per-edge wave-uniform scalars
    int srcs[MSG_T], dsts[MSG_T];
    float eas[MSG_T][12];
#pragma unroll
    for (int t = 0; t < MSG_T; ++t) {
        int e = ebase + t;
        srcs[t] = __builtin_amdgcn_readfirstlane(eidx[e]);
        dsts[t] = __builtin_amdgcn_readfirstlane(eidx[EE + e]);
        const float* p = edge_attr + (size_t)e * FB;
#pragma unroll
        for (int b = 0; b < 12; ++b) eas[t][b] = uni(p[b]);
    }

    // x rows as float4 chunks spread over lanes (lane l holds chunk min(l,18))
    float xfr[MSG_T][4];
    {
        int ch = lane < 19 ? lane : 18;
#pragma unroll
        for (int t = 0; t < MSG_T; ++t) {
            float4 v = *(const float4*)(xp + (size_t)srcs[t] * XPAD + ch * 4);
            xfr[t][0] = v.x; xfr[t][1] = v.y; xfr[t][2] = v.z; xfr[t][3] = v.w;
        }
    }

    const int c1 = lane;
    const int c2 = (lane < 36) ? lane + 64 : 99;   // clamped dup, not written

    float acc[MSG_T][2];
#pragma unroll
    for (int t = 0; t < MSG_T; ++t) { acc[t][0] = 0.f; acc[t][1] = 0.f; }

    const float* gtile = W1g;
#pragma unroll 1
    for (int tile = 0; tile < NTILES; ++tile) {
        __syncthreads();                           // LDS reuse fence
#pragma unroll
        for (int r = 0; r < 8; ++r) {              // stage 64 KB
            int off = (r * 512 + tid) * 4;
            *(float4*)(wlds + off) = *(const float4*)(gtile + off);
        }
        __syncthreads();
        gtile += TILE_DW;

        const int xlb = tile * 3;
        const float* w0 = wlds;
        const float* w1 = wlds + TOFF_W1;
        const float* w2 = wlds + TOFF_W2;
        const float* bb = wlds + TOFF_B;
#pragma unroll
        for (int il = 0; il < IT; ++il) {
            const int r1 = (il * 100 + c1) * 4;
            const int r2 = (il * 100 + c2) * 4;
            float4 a10 = *(const float4*)(w0 + r1);
            float4 a11 = *(const float4*)(w1 + r1);
            float4 a12 = *(const float4*)(w2 + r1);
            float  b1v = bb[il * 100 + c1];
            float4 a20 = *(const float4*)(w0 + r2);
            float4 a21 = *(const float4*)(w1 + r2);
            float4 a22 = *(const float4*)(w2 + r2);
            float  b2v = bb[il * 100 + c2];
            const int xl = xlb + (il >> 2);
#pragma unroll
            for (int t = 0; t < MSG_T; ++t) {
                float xv = bcast_lane(xfr[t][il & 3], xl);
                float z1 = b1v;
                z1 = fmaf(eas[t][0],  a10.x, z1);
                z1 = fmaf(eas[t][1],  a10.y, z1);
                z1 = fmaf(eas[t][2],  a10.z, z1);
                z1 = fmaf(eas[t][3],  a10.w, z1);
                z1 = fmaf(eas[t][4],  a11.x, z1);
                z1 = fmaf(eas[t][5],  a11.y, z1);
                z1 = fmaf(eas[t][6],  a11.z, z1);
                z1 = fmaf(eas[t][7],  a11.w, z1);
                z1 = fmaf(eas[t][8],  a12.x, z1);
                z1 = fmaf(eas[t][9],  a12.y, z1);
                z1 = fmaf(eas[t][10], a12.z, z1);
                z1 = fmaf(eas[t][11], a12.w, z1);
                z1 = fmaxf(z1, 0.f);
                acc[t][0] = fmaf(xv, z1, acc[t][0]);
                float z2 = b2v;
                z2 = fmaf(eas[t][0],  a20.x, z2);
                z2 = fmaf(eas[t][1],  a20.y, z2);
                z2 = fmaf(eas[t][2],  a20.z, z2);
                z2 = fmaf(eas[t][3],  a20.w, z2);
                z2 = fmaf(eas[t][4],  a21.x, z2);
                z2 = fmaf(eas[t][5],  a21.y, z2);
                z2 = fmaf(eas[t][6],  a21.z, z2);
                z2 = fmaf(eas[t][7],  a21.w, z2);
                z2 = fmaf(eas[t][8],  a22.x, z2);
                z2 = fmaf(eas[t][9],  a22.y, z2);
                z2 = fmaf(eas[t][10], a22.z, z2);
                z2 = fmaf(eas[t][11], a22.w, z2);
                z2 = fmaxf(z2, 0.f);
                acc[t][1] = fmaf(xv, z2, acc[t][1]);
            }
        }
    }

#pragma unroll
    for (int t = 0; t < MSG_T; ++t) {
        atomicAdd(&aggT[(size_t)c1 * NN + dsts[t]], acc[t][0]);
        if (lane < 36)
            atomicAdd(&aggT[(size_t)c2 * NN + dsts[t]], acc[t][1]);
    }
}

// Fused root + BN-stats + pool. h = relu(x@W_root + aggT + bias) is never
// stored: per-channel sum/sumsq -> sacc (stats), per-(g,c) sums -> S (pool).
__global__ __launch_bounds__(256, 4) void root_kernel(
    const float* __restrict__ xp, const float* __restrict__ W_root,
    const float* __restrict__ bias, const float* __restrict__ aggT,
    const int* __restrict__ batch, float* __restrict__ S,
    float* __restrict__ sacc)
{
    __shared__ float wr[FA * 12];   // 12-padded rows, 16B-aligned

    const int nb = blockIdx.x / 10;
    const int cg = blockIdx.x - nb * 10;           // 0..9
    const int cbase = __builtin_amdgcn_readfirstlane(cg * 10);

    for (int t = threadIdx.x; t < FA * 10; t += 256) {
        int i = t / 10, j = t - i * 10;
        wr[i * 12 + j] = W_root[i * CC + cbase + j];
    }
    __syncthreads();

    const int n = nb * 256 + threadIdx.x;
    const bool ok = (n < NN);
    const int nc = ok ? n : NN - 1;
    const float4* xr4 = (const float4*)(xp + (size_t)nc * XPAD);
    const int g = batch[nc];

    float acc[10];
#pragma unroll
    for (int j = 0; j < 10; ++j) acc[j] = 0.f;

    float4 cur = xr4[0];
#pragma unroll 1
    for (int k = 0; k < 18; ++k) {
        float4 nxt = xr4[k + 1];
        float xiv[4] = {cur.x, cur.y, cur.z, cur.w};
#pragma unroll
        for (int u = 0; u < 4; ++u) {
            const int i = k * 4 + u;
            float4 v0 = *(const float4*)&wr[i * 12];
            float4 v1 = *(const float4*)&wr[i * 12 + 4];
            float4 v2 = *(const float4*)&wr[i * 12 + 8];
            float wj[10] = {v0.x, v0.y, v0.z, v0.w,
                            v1.x, v1.y, v1.z, v1.w, v2.x, v2.y};
#pragma unroll
            for (int j = 0; j < 10; ++j) acc[j] = fmaf(xiv[u], wj[j], acc[j]);
        }
        cur = nxt;
    }
    {
        float xiv[3] = {cur.x, cur.y, cur.z};
#pragma unroll
        for (int u = 0; u < 3; ++u) {
            const int i = 72 + u;
            float4 v0 = *(const float4*)&wr[i * 12];
            float4 v1 = *(const float4*)&wr[i * 12 + 4];
            float4 v2 = *(const float4*)&wr[i * 12 + 8];
            float wj[10] = {v0.x, v0.y, v0.z, v0.w,
                            v1.x, v1.y, v1.z, v1.w, v2.x, v2.y};
#pragma unroll
            for (int j = 0; j < 10; ++j) acc[j] = fmaf(xiv[u], wj[j], acc[j]);
        }
    }

    const int lane = threadIdx.x & 63;
#pragma unroll
    for (int j = 0; j < 10; ++j) {
        const int c = cbase + j;
        float h = 0.f;
        if (ok) {
            h = fmaxf(acc[j] + bias[c] + aggT[(size_t)c * NN + n], 0.f);
            atomicAdd(&S[(size_t)c * GG + g], h);
        }
        float s = h, s2 = h * h;
#pragma unroll
        for (int o = 32; o > 0; o >>= 1) {
            s  += __shfl_down(s, o);
            s2 += __shfl_down(s2, o);
        }
        if (lane == 0) {
            atomicAdd(&sacc[c], s);
            atomicAdd(&sacc[CC + c], s2);
        }
    }
}

// out[g] = relu(A_c*S[c,g] + cnt_g*(beta_c - A_c*mean_c)) . W_out + b_out
__global__ __launch_bounds__(128) void out_kernel(
    const float* __restrict__ S, const float* __restrict__ sacc,
    const float* __restrict__ gamma, const float* __restrict__ beta,
    const int* __restrict__ start, const float* __restrict__ W_out,
    const float* __restrict__ b_out, float* __restrict__ out)
{
    const int g = blockIdx.x;
    const int c = threadIdx.x;
    float v = 0.f;
    if (c < CC) {
        float mean = sacc[c] / NN;
        float var = sacc[CC + c] / NN - mean * mean;
        float rstd = rsqrtf(var + BN_EPS);
        float A = gamma[c] * rstd;
        float B = beta[c] - A * mean;
        float cnt = (float)(start[g + 1] - start[g]);
        float pooled = fmaf(A, S[(size_t)c * GG + g], cnt * B);
        v = fmaxf(pooled, 0.f) * W_out[c];
    }
    __shared__ float sh[128];
    sh[threadIdx.x] = v;
    __syncthreads();
    for (int o = 64; o > 0; o >>= 1) {
        if (threadIdx.x < o) sh[threadIdx.x] += sh[threadIdx.x + o];
        __syncthreads();
    }
    if (threadIdx.x == 0) out[g] = sh[0] + b_out[0];
}

extern "C" void kernel_launch(void* const* d_in, const int* in_sizes, int n_in,
                              void* d_out, int out_size, void* d_ws, size_t ws_size,
                              hipStream_t stream)
{
    const float* x         = (const float*)d_in[0];
    const float* edge_attr = (const float*)d_in[1];
    const float* W1        = (const float*)d_in[2];
    const float* b1        = (const float*)d_in[3];
    const float* W_root    = (const float*)d_in[4];
    const float* bias      = (const float*)d_in[5];
    const float* gamma     = (const float*)d_in[6];
    const float* beta      = (const float*)d_in[7];
    const float* W_out     = (const float*)d_in[8];
    const float* b_out     = (const float*)d_in[9];
    const int*   eidx      = (const int*)d_in[10];
    const int*   batch     = (const int*)d_in[11];

    float* ws    = (float*)d_ws;
    float* W1g   = ws + OFF_W1G;
    float* xp    = ws + OFF_XP;
    float* aggT  = ws + OFF_AGGT;
    float* S     = ws + OFF_S;
    float* sacc  = ws + OFF_SACC;
    int*   start = (int*)(ws + OFF_START);
    float* out   = (float*)d_out;

    hipMemsetAsync(aggT, 0, (size_t)NN * CC * sizeof(float), stream);
    hipMemsetAsync(S, 0, (size_t)(CC * GG + 2 * CC) * sizeof(float), stream);

    {
        int total = NTILES * 15600 + NN + NN * XPAD;
        prep_kernel<<<(total + 255) / 256, 256, 0, stream>>>(
            W1, b1, x, batch, W1g, xp, start);
    }
    msg_kernel<<<EE / (MSG_WAVES * MSG_T), 512, 0, stream>>>(
        xp, edge_attr, W1g, eidx, aggT);
    root_kernel<<<((NN + 255) / 256) * 10, 256, 0, stream>>>(
        xp, W_root, bias, aggT, batch, S, sacc);
    out_kernel<<<GG, 128, 0, stream>>>(S, sacc, gamma, beta, start, W_out, b_out, out);
}